// Round 13
// baseline (380.570 us; speedup 1.0000x reference)
//
#include <hip/hip_runtime.h>
#include <hip/hip_bf16.h>
#include <stdint.h>
#include <stddef.h>

// Problem dims (fixed): B=64, C=128, H=W=56, 3x3 conv pad=1 stride=1.
#define CH 128
#define HH 56
#define WW 56
#define HWPIX (HH*WW)        // 3136
#define NB 64
#define NPIXF 200704.0f      // B*H*W
#define NCONVBLK 896         // 64 samples x 14 tiles (28x8 px)

typedef __attribute__((ext_vector_type(8))) short short8v;    // 8 bf16 -> MFMA A/B frag
typedef __attribute__((ext_vector_type(8))) unsigned short bfv8;
typedef __attribute__((ext_vector_type(4))) unsigned short bfv4;
typedef __attribute__((ext_vector_type(4))) float f32x4;

__device__ __forceinline__ unsigned short f2bf(float f) {
  unsigned int u = __float_as_uint(f);
  u += 0x7fffu + ((u >> 16) & 1u);            // RNE
  return (unsigned short)(u >> 16);
}
__device__ __forceinline__ float bf2f(unsigned short s) {
  return __uint_as_float(((unsigned int)s) << 16);
}

// ---------------------------------------------------------------------------
// K1: x NCHW fp32 -> NHWC bf16 (LDS transpose, coalesced 16B/lane writes).
__global__ __launch_bounds__(256)
void prep_x(const float* __restrict__ x, unsigned short* __restrict__ xT) {
  __shared__ unsigned short tile[4 * 56 * 128];
  const int bid = blockIdx.x;
  const int b = bid / 14, hq = bid % 14;
  const int hl = threadIdx.x >> 6;
  const int h = hq * 4 + hl;
  const int w = threadIdx.x & 63;
  if (w < WW) {
    const float* src = x + (size_t)b * CH * HWPIX + h * WW + w;
    const int pos = hl * WW + w;
    #pragma unroll 4
    for (int c0 = 0; c0 < CH; c0 += 8) {
      bfv8 v;
      #pragma unroll
      for (int k = 0; k < 8; ++k) v[k] = f2bf(src[(size_t)(c0 + k) * HWPIX]);
      const int idx = (pos * CH + c0) ^ ((pos & 7) << 3);
      *(bfv8*)(tile + idx) = v;
    }
  }
  __syncthreads();
  unsigned short* out = xT + (size_t)(b * HH + hq * 4) * WW * CH;
  #pragma unroll
  for (int j = 0; j < 14; ++j) {
    const int u = j * 256 + threadIdx.x;
    const int idx = (u * 8) ^ (((u >> 4) & 7) << 3);
    *(bfv8*)(out + u * 8) = *(const bfv8*)(tile + idx);
  }
}

// ---------------------------------------------------------------------------
// K2: weights [B,O,I,3,3] fp32 -> [B,tap,O,I] bf16 (dense reads, 16B writes).
__global__ __launch_bounds__(256)
void prep_w(const float* __restrict__ w1, const float* __restrict__ w2,
            unsigned short* __restrict__ o1, unsigned short* __restrict__ o2) {
  __shared__ unsigned short lw[18432];
  const int id = blockIdx.x;
  const int which = id >> 9;
  const int b = (id >> 3) & 63, ck = id & 7;
  const float* src = (which ? w2 : w1) + ((size_t)b * 16384 + ck * 2048) * 9;
  unsigned short* dst = (which ? o2 : o1);
  const int t = threadIdx.x;
  #pragma unroll
  for (int j = 0; j < 72; ++j)
    lw[j * 256 + t] = f2bf(src[j * 256 + t]);
  __syncthreads();
  const int ol = t >> 4, oct = t & 15;
  #pragma unroll
  for (int tap = 0; tap < 9; ++tap) {
    bfv8 v;
    #pragma unroll
    for (int k = 0; k < 8; ++k) v[k] = lw[(ol * 128 + oct * 8 + k) * 9 + tap];
    *(bfv8*)(dst + ((size_t)(b * 9 + tap) * CH + ck * 16 + ol) * CH + oct * 8) = v;
  }
}

// ---------------------------------------------------------------------------
// K3/K5: per-sample conv, implicit GEMM.
// R21: 28x8 TILE (224 px/block). R20 CONFIRMED the VMEM weight-gll count as
// the serializer: blocks 3136->1792 (gll/CU 3528->2016) gave conv 153->114,
// matching the ~26ns/gll linear model. This round halves gll/CU again
// (blocks ->896; every block still fetches its sample's full 294KB weights).
// Model predicts conv ~88us. Cost: patch 300 pos (81.6KB) -> LDS 107KB ->
// 1 block/CU = 1 wave/SIMD -- accepted: R16 proved TLP is a weak lever
// (+50% waves -> +1.3%), and per-stage self-work grows to 28 MFMA + 16
// ds_read (~330cyc) vs 2 glls. acc[2][14]=112 + ~90 arch = ~202; declare
// (256,1) (budget 512) -> zero spill risk. Pipeline identical to R17/R20
// (3-buf, depth-2, SBs, vmcnt(4)).
// Predict: conv 85-110, MfmaUtil 24-30, VGPR 150-210, FETCH ~36MB
// (inflation = spill = abort), occ ~10% (accepted). Pre-committed null:
// conv >=120 -> 1-wave/SIMD serialization ate the savings; revert to R20
// geometry; next lever = cross-wave weight sharing or declare converged.
template<bool FUSE>
__global__ __launch_bounds__(256, 1)
void conv_kernel(const unsigned short* __restrict__ in,
                 const unsigned short* __restrict__ wt,
                 unsigned short* __restrict__ outp,
                 float* __restrict__ partials,
                 const float* __restrict__ tab) {   // [256]: scale | shift (FUSE)
  __shared__ __align__(16) unsigned short patch[40800];  // 300 pos x 136
  __shared__ __align__(16) unsigned short wbuf[12288];   // 4 wv x 3 buf x 1024
  __shared__ float sacc[256];                            // sum[128] | sumsq[128]
  const int xcd = blockIdx.x & 7;
  const int q = blockIdx.x >> 3;                    // 0..111
  const int s = q / 14;
  const int tile = q - s * 14;                      // 0..13
  const int b = s * 8 + xcd;
  const int ty = tile / 7, tx = tile % 7;
  const int h0 = ty * 28, w0 = tx * 8;
  const int t = threadIdx.x;

  const int lane = t & 63, wv = t >> 6;
  const int lrow = lane & 15, lgrp = lane >> 4;
  const int px = lrow & 7, pyl = lrow >> 3;

  sacc[t] = 0.0f;

  // Per-lane global source = lane's A-frag: W[o=wv*32+lrow][lgrp*8..+8].
  // gll writes lane l at LDS base + l*16 -> image IS the frag layout.
  const unsigned short* wsrc =
      wt + (size_t)b * 9 * CH * CH + (wv * 32 + lrow) * CH + lgrp * 8;

  // STAGE(S,P): stage S (tap=S>>2, ic=S&3; 32 O x 32 I = 2KB/wave) into
  // wave-private buffer P. instr0: O rows +0..15; instr1: +16..31.
#define STAGE(S, P) { \
    const unsigned short* g_ = wsrc + ((S) >> 2) * (CH * CH) + ((S) & 3) * 32; \
    unsigned short* l_ = wbuf + (wv * 3 + (P)) * 1024; \
    __builtin_amdgcn_global_load_lds( \
        (const __attribute__((address_space(1))) void*)g_, \
        (__attribute__((address_space(3))) void*)l_, 16, 0, 0); \
    __builtin_amdgcn_global_load_lds( \
        (const __attribute__((address_space(1))) void*)(g_ + 16 * CH), \
        (__attribute__((address_space(3))) void*)(l_ + 512), 16, 0, 0); \
  }

  // Issue stage 0 before patch staging; the barrier's vmcnt(0) drain
  // guarantees it resident after sync.
  STAGE(0, 0)

  // Patch staging: 300 positions x 2 halves of 64ch = 600 items.
  for (int u = t; u < 600; u += 256) {
    const int row = u >> 1, half = u & 1;
    const int dh = row / 10, dw = row - dh * 10;
    const int h = h0 + dh - 1, w = w0 + dw - 1;
    unsigned short* ld = &patch[row * 136 + half * 64];
    if (h >= 0 && h < HH && w >= 0 && w < WW) {
      const unsigned short* src = in + ((size_t)((b * HH + h) * WW + w)) * CH + half * 64;
      if (FUSE) {
        #pragma unroll
        for (int j = 0; j < 8; ++j) {
          const bfv8 v = *(const bfv8*)(src + j * 8);
          bfv8 o;
          #pragma unroll
          for (int k = 0; k < 8; ++k) {
            const int c = half * 64 + j * 8 + k;
            const float f = fmaxf(bf2f(v[k]) * tab[c] + tab[CH + c], 0.0f);
            o[k] = f2bf(f);
          }
          *(bfv8*)(ld + j * 8) = o;
        }
      } else {
        #pragma unroll
        for (int j = 0; j < 8; ++j)
          *(bfv8*)(ld + j * 8) = *(const bfv8*)(src + j * 8);
      }
    } else {
      const bfv8 z = {0, 0, 0, 0, 0, 0, 0, 0};
      #pragma unroll
      for (int j = 0; j < 8; ++j) *(bfv8*)(ld + j * 8) = z;
    }
  }
  __syncthreads();

  f32x4 acc[2][14];
  #pragma unroll
  for (int m = 0; m < 2; ++m)
    #pragma unroll
    for (int n = 0; n < 14; ++n) acc[m][n] = (f32x4){0.f, 0.f, 0.f, 0.f};

  // Refill the pipeline after the barrier drain: stage 1 in flight now.
  STAGE(1, 1)

  // COMPUTE(S,P): 2 A-frags lane-linear from wave-private buf P
  // (conflict-free), 14 B-frags from patch, 28 MFMA (K=32 chunk ic).
#define COMPUTE(S, P) { \
    const int tap_ = (S) >> 2, ic_ = (S) & 3; \
    const int pb_ = (pyl + tap_ / 3) * 10 + px + tap_ % 3; \
    const unsigned short* ab_ = wbuf + (wv * 3 + (P)) * 1024 + lane * 8; \
    const short8v a0_ = *(const short8v*)(ab_); \
    const short8v a1_ = *(const short8v*)(ab_ + 512); \
    _Pragma("unroll") \
    for (int nf = 0; nf < 14; ++nf) { \
      const short8v bfr = *(const short8v*)( \
          &patch[(pb_ + nf * 20) * 136 + ic_ * 32 + lgrp * 8]); \
      acc[0][nf] = __builtin_amdgcn_mfma_f32_16x16x32_bf16(a0_, bfr, acc[0][nf], 0, 0, 0); \
      acc[1][nf] = __builtin_amdgcn_mfma_f32_16x16x32_bf16(a1_, bfr, acc[1][nf], 0, 0, 0); \
    } }

  // RUN(S): [SB] issue S+2 -> wait vmcnt(4) (S resident; S+1,S+2 in flight)
  // [SB] compute S. Depth-2, 3-buffer rotation (proven correct R17/R20).
#define RUN(S) \
    __builtin_amdgcn_sched_barrier(0); \
    STAGE((S) + 2, ((S) + 2) % 3) \
    asm volatile("s_waitcnt vmcnt(4)" ::: "memory"); \
    __builtin_amdgcn_sched_barrier(0); \
    COMPUTE(S, (S) % 3)

  RUN(0)  RUN(1)  RUN(2)  RUN(3)  RUN(4)  RUN(5)  RUN(6)  RUN(7)
  RUN(8)  RUN(9)  RUN(10) RUN(11) RUN(12) RUN(13) RUN(14) RUN(15)
  RUN(16) RUN(17) RUN(18) RUN(19) RUN(20) RUN(21) RUN(22) RUN(23)
  RUN(24) RUN(25) RUN(26) RUN(27) RUN(28) RUN(29) RUN(30) RUN(31)
  RUN(32) RUN(33)
  // Tail: stages 34,35 already in flight.
  __builtin_amdgcn_sched_barrier(0);
  asm volatile("s_waitcnt vmcnt(2)" ::: "memory");
  __builtin_amdgcn_sched_barrier(0);
  COMPUTE(34, 1)
  __builtin_amdgcn_sched_barrier(0);
  asm volatile("s_waitcnt vmcnt(0)" ::: "memory");
  __builtin_amdgcn_sched_barrier(0);
  COMPUTE(35, 2)
#undef RUN
#undef COMPUTE
#undef STAGE

  __syncthreads();   // patch reads done everywhere; reuse patch as output buffer

  // Stage D into LDS: obuf[pixel p 0..223][ch 0..127] bf16, byte ^= swizzle.
  char* obuf = (char*)patch;
  #pragma unroll
  for (int mf = 0; mf < 2; ++mf) {
    #pragma unroll
    for (int nf = 0; nf < 14; ++nf) {
      const f32x4 v = acc[mf][nf];
      bfv4 pk;
      #pragma unroll
      for (int r = 0; r < 4; ++r) pk[r] = f2bf(v[r]);
      const int p = (nf * 2 + pyl) * 8 + px;
      const int ch = wv * 32 + mf * 16 + lgrp * 4;
      int byte = p * 256 + ch * 2;
      byte ^= ((byte >> 8) & 3) << 5;
      *(bfv4*)(obuf + byte) = pk;
    }
  }

  // Fused BN stat partials: shuffle-reduce over the 16 pixel lanes,
  // LDS-accumulate, then ONE non-atomic 256-float row per block.
  #pragma unroll
  for (int mf = 0; mf < 2; ++mf) {
    f32x4 sv4 = {0.f, 0.f, 0.f, 0.f}, qv4 = {0.f, 0.f, 0.f, 0.f};
    #pragma unroll
    for (int nf = 0; nf < 14; ++nf) {
      const f32x4 v = acc[mf][nf];
      sv4 += v;
      qv4 += v * v;
    }
    #pragma unroll
    for (int r = 0; r < 4; ++r) {
      float sv = sv4[r], qv = qv4[r];
      sv += __shfl_xor(sv, 1, 64);  qv += __shfl_xor(qv, 1, 64);
      sv += __shfl_xor(sv, 2, 64);  qv += __shfl_xor(qv, 2, 64);
      sv += __shfl_xor(sv, 4, 64);  qv += __shfl_xor(qv, 4, 64);
      sv += __shfl_xor(sv, 8, 64);  qv += __shfl_xor(qv, 8, 64);
      if (lrow == 0) {
        const int ch = wv * 32 + mf * 16 + lgrp * 4 + r;
        atomicAdd(&sacc[ch], sv);        // LDS atomic, 8 per thread-group
        atomicAdd(&sacc[CH + ch], qv);
      }
    }
  }

  __syncthreads();

  partials[(size_t)blockIdx.x * 256 + t] = sacc[t];

  // Copy out: 14 passes x 256 threads x 16B (224 px x 128 ch).
  #pragma unroll
  for (int j = 0; j < 14; ++j) {
    const int u = j * 256 + t;           // 16B unit index, 0..3583
    int byte = u * 16;
    byte ^= ((byte >> 8) & 3) << 5;
    const bfv8 v = *(const bfv8*)(obuf + byte);
    const int pix = u >> 4, py = pix >> 3, pxx = pix & 7;
    *(bfv8*)(outp + ((size_t)((b * HH + h0 + py) * WW + (w0 + pxx))) * CH +
             (u & 15) * 8) = v;
  }
}

// ---------------------------------------------------------------------------
// K-red: reduce partials[896][256] -> st[256]. 32 blocks x 256 thr.
__global__ __launch_bounds__(256)
void stat_reduce(const float* __restrict__ partials, float* __restrict__ st) {
  const int t = threadIdx.x;
  float s = 0.0f;
  const int i0 = blockIdx.x * (NCONVBLK / 32);
  for (int i = 0; i < NCONVBLK / 32; ++i)
    s += partials[(size_t)(i0 + i) * 256 + t];
  atomicAdd(&st[t], s);
}

// ---------------------------------------------------------------------------
// K4/K6: per-channel BN stats -> scale/shift tables.
__global__ __launch_bounds__(128)
void bn_stats(const float* __restrict__ st, const float* __restrict__ gamma,
              const float* __restrict__ beta, float* __restrict__ tab) {
  const int c = threadIdx.x;
  const float inv = 1.0f / NPIXF;
  const float mean = st[c] * inv;
  const float var = st[CH + c] * inv - mean * mean;
  const float s = gamma[c] / sqrtf(var + 1e-5f);
  tab[c] = s;
  tab[CH + c] = beta[c] - mean * s;
}

// ---------------------------------------------------------------------------
// K7: out = relu(scale2*y2 + shift2 + residual), NHWC bf16 -> NCHW fp32.
// BF16RES: residual from xT (bf16 NHWC, 51MB) instead of x (fp32 NCHW, 205MB).
template<bool BF16RES>
__global__ __launch_bounds__(256)
void final_kernel(const unsigned short* __restrict__ y2,
                  const unsigned short* __restrict__ xbf,
                  const float* __restrict__ x,
                  const float* __restrict__ tab, float* __restrict__ out) {
  const int bid = blockIdx.x;
  const int b = bid / 14, hq = bid % 14;
  const int h = hq * 4 + (threadIdx.x >> 6);
  const int w = threadIdx.x & 63;
  if (w >= WW) return;
  const unsigned short* ys = y2 + ((size_t)(b * HH + h) * WW + w) * CH;
  const unsigned short* rs = xbf + ((size_t)(b * HH + h) * WW + w) * CH;
  const float* xs = x + (size_t)b * CH * HWPIX + h * WW + w;
  float* os = out + (size_t)b * CH * HWPIX + h * WW + w;
  #pragma unroll 4
  for (int c = 0; c < CH; ++c) {
    const float v = bf2f(ys[c]);
    const float res = BF16RES ? bf2f(rs[c]) : xs[(size_t)c * HWPIX];
    const float r = v * tab[c] + tab[CH + c] + res;
    os[(size_t)c * HWPIX] = fmaxf(r, 0.0f);
  }
}

// ---------------------------------------------------------------------------
extern "C" void kernel_launch(void* const* d_in, const int* in_sizes, int n_in,
                              void* d_out, int out_size, void* d_ws, size_t ws_size,
                              hipStream_t stream) {
  const float* x  = (const float*)d_in[0];
  const float* w1 = (const float*)d_in[1];
  const float* w2 = (const float*)d_in[2];
  const float* g1 = (const float*)d_in[3];
  const float* b1 = (const float*)d_in[4];
  const float* g2 = (const float*)d_in[5];
  const float* b2 = (const float*)d_in[6];
  float* out = (float*)d_out;

  // Workspace layout (bytes):
  //   xT   0            51,380,224
  //   y1   51,380,224   51,380,224
  //   w1b  102,760,448  18,874,368
  //   w2b  121,634,816  18,874,368
  //   p1   140,509,184  3,211,264   (896 x 256 floats used)
  //   p2   143,720,448  3,211,264
  //   st   146,931,712  4,096   (st1|st2|tab1|tab2, 256 floats each)
  //   y2   146,935,808  51,380,224  (optional, if ws_size allows)
  char* ws = (char*)d_ws;
  unsigned short* xT  = (unsigned short*)(ws);
  unsigned short* y1  = (unsigned short*)(ws + 51380224);
  unsigned short* w1b = (unsigned short*)(ws + 102760448);
  unsigned short* w2b = (unsigned short*)(ws + 121634816);
  float*          p1  = (float*)(ws + 140509184);
  float*          p2  = (float*)(ws + 143720448);
  float*          st  = (float*)(ws + 146931712);
  const bool sepY2 = ws_size >= (size_t)146935808 + 51380224;
  unsigned short* y2  = sepY2 ? (unsigned short*)(ws + 146935808) : xT;

  (void)hipMemsetAsync(st, 0, 2048, stream);  // zero st1+st2

  hipLaunchKernelGGL(prep_x, dim3(NB * 14), dim3(256), 0, stream, x, xT);
  hipLaunchKernelGGL(prep_w, dim3(1024), dim3(256), 0, stream, w1, w2, w1b, w2b);
  hipLaunchKernelGGL((conv_kernel<false>), dim3(NCONVBLK), dim3(256), 0, stream,
                     xT, w1b, y1, p1, (const float*)nullptr);
  hipLaunchKernelGGL(stat_reduce, dim3(32), dim3(256), 0, stream, p1, st);
  hipLaunchKernelGGL(bn_stats, dim3(1), dim3(128), 0, stream, st, g1, b1, st + 512);
  hipLaunchKernelGGL((conv_kernel<true>), dim3(NCONVBLK), dim3(256), 0, stream,
                     y1, w2b, y2, p2, st + 512);
  hipLaunchKernelGGL(stat_reduce, dim3(32), dim3(256), 0, stream, p2, st + 256);
  hipLaunchKernelGGL(bn_stats, dim3(1), dim3(128), 0, stream, st + 256, g2, b2, st + 768);
  if (sepY2) {
    hipLaunchKernelGGL((final_kernel<true>), dim3(NB * 14), dim3(256), 0, stream,
                       y2, xT, x, st + 768, out);
  } else {
    hipLaunchKernelGGL((final_kernel<false>), dim3(NB * 14), dim3(256), 0, stream,
                       y2, xT, x, st + 768, out);
  }
}

// Round 14
// 348.004 us; speedup vs baseline: 1.0936x; 1.0936x over previous
//
#include <hip/hip_runtime.h>
#include <hip/hip_bf16.h>
#include <stdint.h>
#include <stddef.h>

// Problem dims (fixed): B=64, C=128, H=W=56, 3x3 conv pad=1 stride=1.
#define CH 128
#define HH 56
#define WW 56
#define HWPIX (HH*WW)        // 3136
#define NB 64
#define NPIXF 200704.0f      // B*H*W
#define NCONVBLK 896         // 64 samples x 14 tiles (28x8 px)

typedef __attribute__((ext_vector_type(8))) short short8v;    // 8 bf16 -> MFMA A/B frag
typedef __attribute__((ext_vector_type(8))) unsigned short bfv8;
typedef __attribute__((ext_vector_type(4))) unsigned short bfv4;
typedef __attribute__((ext_vector_type(4))) float f32x4;

__device__ __forceinline__ unsigned short f2bf(float f) {
  unsigned int u = __float_as_uint(f);
  u += 0x7fffu + ((u >> 16) & 1u);            // RNE
  return (unsigned short)(u >> 16);
}
__device__ __forceinline__ float bf2f(unsigned short s) {
  return __uint_as_float(((unsigned int)s) << 16);
}

// ---------------------------------------------------------------------------
// K1: x NCHW fp32 -> NHWC bf16 (LDS transpose, coalesced 16B/lane writes).
__global__ __launch_bounds__(256)
void prep_x(const float* __restrict__ x, unsigned short* __restrict__ xT) {
  __shared__ unsigned short tile[4 * 56 * 128];
  const int bid = blockIdx.x;
  const int b = bid / 14, hq = bid % 14;
  const int hl = threadIdx.x >> 6;
  const int h = hq * 4 + hl;
  const int w = threadIdx.x & 63;
  if (w < WW) {
    const float* src = x + (size_t)b * CH * HWPIX + h * WW + w;
    const int pos = hl * WW + w;
    #pragma unroll 4
    for (int c0 = 0; c0 < CH; c0 += 8) {
      bfv8 v;
      #pragma unroll
      for (int k = 0; k < 8; ++k) v[k] = f2bf(src[(size_t)(c0 + k) * HWPIX]);
      const int idx = (pos * CH + c0) ^ ((pos & 7) << 3);
      *(bfv8*)(tile + idx) = v;
    }
  }
  __syncthreads();
  unsigned short* out = xT + (size_t)(b * HH + hq * 4) * WW * CH;
  #pragma unroll
  for (int j = 0; j < 14; ++j) {
    const int u = j * 256 + threadIdx.x;
    const int idx = (u * 8) ^ (((u >> 4) & 7) << 3);
    *(bfv8*)(out + u * 8) = *(const bfv8*)(tile + idx);
  }
}

// ---------------------------------------------------------------------------
// K2: weights [B,O,I,3,3] fp32 -> [B,tap,O,I] bf16 (dense reads, 16B writes).
__global__ __launch_bounds__(256)
void prep_w(const float* __restrict__ w1, const float* __restrict__ w2,
            unsigned short* __restrict__ o1, unsigned short* __restrict__ o2) {
  __shared__ unsigned short lw[18432];
  const int id = blockIdx.x;
  const int which = id >> 9;
  const int b = (id >> 3) & 63, ck = id & 7;
  const float* src = (which ? w2 : w1) + ((size_t)b * 16384 + ck * 2048) * 9;
  unsigned short* dst = (which ? o2 : o1);
  const int t = threadIdx.x;
  #pragma unroll
  for (int j = 0; j < 72; ++j)
    lw[j * 256 + t] = f2bf(src[j * 256 + t]);
  __syncthreads();
  const int ol = t >> 4, oct = t & 15;
  #pragma unroll
  for (int tap = 0; tap < 9; ++tap) {
    bfv8 v;
    #pragma unroll
    for (int k = 0; k < 8; ++k) v[k] = lw[(ol * 128 + oct * 8 + k) * 9 + tap];
    *(bfv8*)(dst + ((size_t)(b * 9 + tap) * CH + ck * 16 + ol) * CH + oct * 8) = v;
  }
}

// ---------------------------------------------------------------------------
// K3/K5: per-sample conv, implicit GEMM.
// R22: 28x8 TILE + K-SPLIT PATCH (both levers at once). Measured levers:
// gll count (R20: -43% glls -> -39us at 2 blk/CU) and co-residency (R21:
// 1 blk/CU costs ~+34us). R21's 128-ch patch (81.6KB) forced 1 blk/CU.
// Fix: stage the patch 64 channels at a time (300 pos x 68-stride = 40.8KB);
// phase 0 runs 18 stages (9 taps x 2 ic-chunks) on I in [0,64), restage,
// phase 1 runs I in [64,128). acc[2][14] carries across phases (K-accum).
// Input HBM bytes unchanged (each phase reads its own 64ch). Weight glls
// stay at R21's 1008/CU. LDS 40.8K+24.6K wbuf+1K = 66.4KB -> 2 blocks/CU.
// Combined regs: 112 acc + ~132 arch = 244 <= 256 budget at (256,2) (R19
// proved arch 132 clean at N=2). Cost: 1 restage + 2 barriers per block.
// Epilogue: two 112-px obuf passes (28.7KB <= patch region).
// Predict: conv 122->88-105, MfmaUtil 24-30, occ ~18-20, VGPR 130-144,
// FETCH ~36MB (>60 = spill = abort). Pre-committed null: conv >=115 ->
// revert R20, conv converged, pivot aux.
template<bool FUSE>
__global__ __launch_bounds__(256, 2)
void conv_kernel(const unsigned short* __restrict__ in,
                 const unsigned short* __restrict__ wt,
                 unsigned short* __restrict__ outp,
                 float* __restrict__ partials,
                 const float* __restrict__ tab) {   // [256]: scale | shift (FUSE)
  __shared__ __align__(16) unsigned short patch[20400];  // 300 pos x 68 (64ch)
  __shared__ __align__(16) unsigned short wbuf[12288];   // 4 wv x 3 buf x 1024
  __shared__ float sacc[256];                            // sum[128] | sumsq[128]
  const int xcd = blockIdx.x & 7;
  const int q = blockIdx.x >> 3;                    // 0..111
  const int s = q / 14;
  const int tile = q - s * 14;                      // 0..13
  const int b = s * 8 + xcd;
  const int ty = tile / 7, tx = tile % 7;
  const int h0 = ty * 28, w0 = tx * 8;
  const int t = threadIdx.x;

  const int lane = t & 63, wv = t >> 6;
  const int lrow = lane & 15, lgrp = lane >> 4;
  const int px = lrow & 7, pyl = lrow >> 3;

  sacc[t] = 0.0f;

  // Per-lane global source = lane's A-frag: W[o=wv*32+lrow][lgrp*8..+8].
  const unsigned short* wsrc =
      wt + (size_t)b * 9 * CH * CH + (wv * 32 + lrow) * CH + lgrp * 8;

  // Stage S (0..35): phase = S/18, tap = (S%18)>>1, ic = phase*64+(S&1)*32.
  // 32 O x 32 I = 2KB/wave into wave-private buffer P (2 gll instrs).
#define STAGE(S, P) { \
    const unsigned short* g_ = wsrc + (((S) % 18) >> 1) * (CH * CH) + \
                               ((S) / 18) * 64 + ((S) & 1) * 32; \
    unsigned short* l_ = wbuf + (wv * 3 + (P)) * 1024; \
    __builtin_amdgcn_global_load_lds( \
        (const __attribute__((address_space(1))) void*)g_, \
        (__attribute__((address_space(3))) void*)l_, 16, 0, 0); \
    __builtin_amdgcn_global_load_lds( \
        (const __attribute__((address_space(1))) void*)(g_ + 16 * CH), \
        (__attribute__((address_space(3))) void*)(l_ + 512), 16, 0, 0); \
  }

  // Patch staging for channel-half PH: 300 positions x 64 ch (128B each).
#define STAGE_PATCH(PH) { \
    for (int u = t; u < 300; u += 256) { \
      const int dh = u / 10, dw = u - dh * 10; \
      const int h = h0 + dh - 1, w = w0 + dw - 1; \
      unsigned short* ld = &patch[u * 68]; \
      if (h >= 0 && h < HH && w >= 0 && w < WW) { \
        const unsigned short* src = \
            in + ((size_t)((b * HH + h) * WW + w)) * CH + (PH) * 64; \
        if (FUSE) { \
          for (int j = 0; j < 8; ++j) { \
            const bfv8 v = *(const bfv8*)(src + j * 8); \
            bfv8 o; \
            for (int k = 0; k < 8; ++k) { \
              const int c = (PH) * 64 + j * 8 + k; \
              o[k] = f2bf(fmaxf(bf2f(v[k]) * tab[c] + tab[CH + c], 0.0f)); \
            } \
            *(bfv8*)(ld + j * 8) = o; \
          } \
        } else { \
          for (int j = 0; j < 8; ++j) \
            *(bfv8*)(ld + j * 8) = *(const bfv8*)(src + j * 8); \
        } \
      } else { \
        const bfv8 z = {0, 0, 0, 0, 0, 0, 0, 0}; \
        for (int j = 0; j < 8; ++j) *(bfv8*)(ld + j * 8) = z; \
      } \
    } }

  // COMPUTE(S,P): 2 A-frags lane-linear from wave-private buf P,
  // 14 B-frags from patch (ic chunk = S&1 within the 64-wide rows), 28 MFMA.
#define COMPUTE(S, P) { \
    const int tap_ = ((S) % 18) >> 1, icl_ = (S) & 1; \
    const int pb_ = (pyl + tap_ / 3) * 10 + px + tap_ % 3; \
    const unsigned short* ab_ = wbuf + (wv * 3 + (P)) * 1024 + lane * 8; \
    const short8v a0_ = *(const short8v*)(ab_); \
    const short8v a1_ = *(const short8v*)(ab_ + 512); \
    _Pragma("unroll") \
    for (int nf = 0; nf < 14; ++nf) { \
      const short8v bfr = *(const short8v*)( \
          &patch[(pb_ + nf * 20) * 68 + icl_ * 32 + lgrp * 8]); \
      acc[0][nf] = __builtin_amdgcn_mfma_f32_16x16x32_bf16(a0_, bfr, acc[0][nf], 0, 0, 0); \
      acc[1][nf] = __builtin_amdgcn_mfma_f32_16x16x32_bf16(a1_, bfr, acc[1][nf], 0, 0, 0); \
    } }

#define RUN(S) \
    __builtin_amdgcn_sched_barrier(0); \
    STAGE((S) + 2, ((S) + 2) % 3) \
    asm volatile("s_waitcnt vmcnt(4)" ::: "memory"); \
    __builtin_amdgcn_sched_barrier(0); \
    COMPUTE(S, (S) % 3)

  // ---- Phase 0: I in [0,64) ----
  STAGE(0, 0)
  STAGE_PATCH(0)
  __syncthreads();

  f32x4 acc[2][14];
  #pragma unroll
  for (int m = 0; m < 2; ++m)
    #pragma unroll
    for (int n = 0; n < 14; ++n) acc[m][n] = (f32x4){0.f, 0.f, 0.f, 0.f};

  STAGE(1, 1)
  RUN(0)  RUN(1)  RUN(2)  RUN(3)  RUN(4)  RUN(5)  RUN(6)  RUN(7)
  RUN(8)  RUN(9)  RUN(10) RUN(11) RUN(12) RUN(13) RUN(14) RUN(15)
  __builtin_amdgcn_sched_barrier(0);
  asm volatile("s_waitcnt vmcnt(2)" ::: "memory");
  __builtin_amdgcn_sched_barrier(0);
  COMPUTE(16, 1)
  __builtin_amdgcn_sched_barrier(0);
  asm volatile("s_waitcnt vmcnt(0)" ::: "memory");
  __builtin_amdgcn_sched_barrier(0);
  COMPUTE(17, 2)

  // ---- Phase boundary: restage patch with I in [64,128) ----
  STAGE(18, 0)            // drained resident by the barrier below
  __syncthreads();        // all phase-0 patch reads done
  STAGE_PATCH(1)
  __syncthreads();        // new patch ready

  STAGE(19, 1)
  RUN(18) RUN(19) RUN(20) RUN(21) RUN(22) RUN(23) RUN(24) RUN(25)
  RUN(26) RUN(27) RUN(28) RUN(29) RUN(30) RUN(31) RUN(32) RUN(33)
  __builtin_amdgcn_sched_barrier(0);
  asm volatile("s_waitcnt vmcnt(2)" ::: "memory");
  __builtin_amdgcn_sched_barrier(0);
  COMPUTE(34, 1)
  __builtin_amdgcn_sched_barrier(0);
  asm volatile("s_waitcnt vmcnt(0)" ::: "memory");
  __builtin_amdgcn_sched_barrier(0);
  COMPUTE(35, 2)
#undef RUN
#undef COMPUTE
#undef STAGE
#undef STAGE_PATCH

  __syncthreads();   // all patch reads done; reuse patch as output buffer

  // Fused BN stat partials (uses acc only; sacc atomics complete before the
  // next barrier).
  #pragma unroll
  for (int mf = 0; mf < 2; ++mf) {
    f32x4 sv4 = {0.f, 0.f, 0.f, 0.f}, qv4 = {0.f, 0.f, 0.f, 0.f};
    #pragma unroll
    for (int nf = 0; nf < 14; ++nf) {
      const f32x4 v = acc[mf][nf];
      sv4 += v;
      qv4 += v * v;
    }
    #pragma unroll
    for (int r = 0; r < 4; ++r) {
      float sv = sv4[r], qv = qv4[r];
      sv += __shfl_xor(sv, 1, 64);  qv += __shfl_xor(qv, 1, 64);
      sv += __shfl_xor(sv, 2, 64);  qv += __shfl_xor(qv, 2, 64);
      sv += __shfl_xor(sv, 4, 64);  qv += __shfl_xor(qv, 4, 64);
      sv += __shfl_xor(sv, 8, 64);  qv += __shfl_xor(qv, 8, 64);
      if (lrow == 0) {
        const int ch = wv * 32 + mf * 16 + lgrp * 4 + r;
        atomicAdd(&sacc[ch], sv);
        atomicAdd(&sacc[CH + ch], qv);
      }
    }
  }

  // Epilogue: two 112-px passes through obuf (28,672B <= patch region).
  char* obuf = (char*)patch;
  #pragma unroll
  for (int a = 0; a < 2; ++a) {
    if (a) __syncthreads();            // previous copy-out reads done
    #pragma unroll
    for (int mf = 0; mf < 2; ++mf) {
      #pragma unroll
      for (int m = 0; m < 7; ++m) {
        const f32x4 v = acc[mf][a * 7 + m];
        bfv4 pk;
        #pragma unroll
        for (int r = 0; r < 4; ++r) pk[r] = f2bf(v[r]);
        const int p = (m * 2 + pyl) * 8 + px;          // 0..111 within pass
        const int ch = wv * 32 + mf * 16 + lgrp * 4;
        int byte = p * 256 + ch * 2;
        byte ^= ((byte >> 8) & 3) << 5;
        *(bfv4*)(obuf + byte) = pk;
      }
    }
    __syncthreads();
    if (a == 0) partials[(size_t)blockIdx.x * 256 + t] = sacc[t];
    // Copy out 112 px x 128 ch = 1792 x 16B units.
    #pragma unroll
    for (int j = 0; j < 7; ++j) {
      const int u = j * 256 + t;
      int byte = u * 16;
      byte ^= ((byte >> 8) & 3) << 5;
      const bfv8 v = *(const bfv8*)(obuf + byte);
      const int pix = u >> 4, py = pix >> 3, pxx = pix & 7;
      *(bfv8*)(outp + ((size_t)((b * HH + h0 + a * 14 + py) * WW + (w0 + pxx))) * CH +
               (u & 15) * 8) = v;
    }
  }
}

// ---------------------------------------------------------------------------
// K-red: reduce partials[896][256] -> st[256]. 32 blocks x 256 thr.
__global__ __launch_bounds__(256)
void stat_reduce(const float* __restrict__ partials, float* __restrict__ st) {
  const int t = threadIdx.x;
  float s = 0.0f;
  const int i0 = blockIdx.x * (NCONVBLK / 32);
  for (int i = 0; i < NCONVBLK / 32; ++i)
    s += partials[(size_t)(i0 + i) * 256 + t];
  atomicAdd(&st[t], s);
}

// ---------------------------------------------------------------------------
// K4/K6: per-channel BN stats -> scale/shift tables.
__global__ __launch_bounds__(128)
void bn_stats(const float* __restrict__ st, const float* __restrict__ gamma,
              const float* __restrict__ beta, float* __restrict__ tab) {
  const int c = threadIdx.x;
  const float inv = 1.0f / NPIXF;
  const float mean = st[c] * inv;
  const float var = st[CH + c] * inv - mean * mean;
  const float s = gamma[c] / sqrtf(var + 1e-5f);
  tab[c] = s;
  tab[CH + c] = beta[c] - mean * s;
}

// ---------------------------------------------------------------------------
// K7: out = relu(scale2*y2 + shift2 + residual), NHWC bf16 -> NCHW fp32.
// BF16RES: residual from xT (bf16 NHWC, 51MB) instead of x (fp32 NCHW, 205MB).
template<bool BF16RES>
__global__ __launch_bounds__(256)
void final_kernel(const unsigned short* __restrict__ y2,
                  const unsigned short* __restrict__ xbf,
                  const float* __restrict__ x,
                  const float* __restrict__ tab, float* __restrict__ out) {
  const int bid = blockIdx.x;
  const int b = bid / 14, hq = bid % 14;
  const int h = hq * 4 + (threadIdx.x >> 6);
  const int w = threadIdx.x & 63;
  if (w >= WW) return;
  const unsigned short* ys = y2 + ((size_t)(b * HH + h) * WW + w) * CH;
  const unsigned short* rs = xbf + ((size_t)(b * HH + h) * WW + w) * CH;
  const float* xs = x + (size_t)b * CH * HWPIX + h * WW + w;
  float* os = out + (size_t)b * CH * HWPIX + h * WW + w;
  #pragma unroll 4
  for (int c = 0; c < CH; ++c) {
    const float v = bf2f(ys[c]);
    const float res = BF16RES ? bf2f(rs[c]) : xs[(size_t)c * HWPIX];
    const float r = v * tab[c] + tab[CH + c] + res;
    os[(size_t)c * HWPIX] = fmaxf(r, 0.0f);
  }
}

// ---------------------------------------------------------------------------
extern "C" void kernel_launch(void* const* d_in, const int* in_sizes, int n_in,
                              void* d_out, int out_size, void* d_ws, size_t ws_size,
                              hipStream_t stream) {
  const float* x  = (const float*)d_in[0];
  const float* w1 = (const float*)d_in[1];
  const float* w2 = (const float*)d_in[2];
  const float* g1 = (const float*)d_in[3];
  const float* b1 = (const float*)d_in[4];
  const float* g2 = (const float*)d_in[5];
  const float* b2 = (const float*)d_in[6];
  float* out = (float*)d_out;

  // Workspace layout (bytes):
  //   xT   0            51,380,224
  //   y1   51,380,224   51,380,224
  //   w1b  102,760,448  18,874,368
  //   w2b  121,634,816  18,874,368
  //   p1   140,509,184  3,211,264   (896 x 256 floats used)
  //   p2   143,720,448  3,211,264
  //   st   146,931,712  4,096   (st1|st2|tab1|tab2, 256 floats each)
  //   y2   146,935,808  51,380,224  (optional, if ws_size allows)
  char* ws = (char*)d_ws;
  unsigned short* xT  = (unsigned short*)(ws);
  unsigned short* y1  = (unsigned short*)(ws + 51380224);
  unsigned short* w1b = (unsigned short*)(ws + 102760448);
  unsigned short* w2b = (unsigned short*)(ws + 121634816);
  float*          p1  = (float*)(ws + 140509184);
  float*          p2  = (float*)(ws + 143720448);
  float*          st  = (float*)(ws + 146931712);
  const bool sepY2 = ws_size >= (size_t)146935808 + 51380224;
  unsigned short* y2  = sepY2 ? (unsigned short*)(ws + 146935808) : xT;

  (void)hipMemsetAsync(st, 0, 2048, stream);  // zero st1+st2

  hipLaunchKernelGGL(prep_x, dim3(NB * 14), dim3(256), 0, stream, x, xT);
  hipLaunchKernelGGL(prep_w, dim3(1024), dim3(256), 0, stream, w1, w2, w1b, w2b);
  hipLaunchKernelGGL((conv_kernel<false>), dim3(NCONVBLK), dim3(256), 0, stream,
                     xT, w1b, y1, p1, (const float*)nullptr);
  hipLaunchKernelGGL(stat_reduce, dim3(32), dim3(256), 0, stream, p1, st);
  hipLaunchKernelGGL(bn_stats, dim3(1), dim3(128), 0, stream, st, g1, b1, st + 512);
  hipLaunchKernelGGL((conv_kernel<true>), dim3(NCONVBLK), dim3(256), 0, stream,
                     y1, w2b, y2, p2, st + 512);
  hipLaunchKernelGGL(stat_reduce, dim3(32), dim3(256), 0, stream, p2, st + 256);
  hipLaunchKernelGGL(bn_stats, dim3(1), dim3(128), 0, stream, st + 256, g2, b2, st + 768);
  if (sepY2) {
    hipLaunchKernelGGL((final_kernel<true>), dim3(NB * 14), dim3(256), 0, stream,
                       y2, xT, x, st + 768, out);
  } else {
    hipLaunchKernelGGL((final_kernel<false>), dim3(NB * 14), dim3(256), 0, stream,
                       y2, xT, x, st + 768, out);
  }
}

// Round 15
// 300.085 us; speedup vs baseline: 1.2682x; 1.1597x over previous
//
#include <hip/hip_runtime.h>
#include <hip/hip_bf16.h>
#include <stdint.h>
#include <stddef.h>

// Problem dims (fixed): B=64, C=128, H=W=56, 3x3 conv pad=1 stride=1.
#define CH 128
#define HH 56
#define WW 56
#define HWPIX (HH*WW)        // 3136
#define NB 64
#define NPIXF 200704.0f      // B*H*W
#define NCONVBLK 896         // 64 samples x 14 tiles (28x8 px)

typedef __attribute__((ext_vector_type(8))) short short8v;    // 8 bf16 -> MFMA A/B frag
typedef __attribute__((ext_vector_type(8))) unsigned short bfv8;
typedef __attribute__((ext_vector_type(4))) unsigned short bfv4;
typedef __attribute__((ext_vector_type(4))) float f32x4;

__device__ __forceinline__ unsigned short f2bf(float f) {
  unsigned int u = __float_as_uint(f);
  u += 0x7fffu + ((u >> 16) & 1u);            // RNE
  return (unsigned short)(u >> 16);
}
__device__ __forceinline__ float bf2f(unsigned short s) {
  return __uint_as_float(((unsigned int)s) << 16);
}

// ---------------------------------------------------------------------------
// K1: x NCHW fp32 -> NHWC bf16 (LDS transpose, coalesced 16B/lane writes).
__global__ __launch_bounds__(256)
void prep_x(const float* __restrict__ x, unsigned short* __restrict__ xT) {
  __shared__ unsigned short tile[4 * 56 * 128];
  const int bid = blockIdx.x;
  const int b = bid / 14, hq = bid % 14;
  const int hl = threadIdx.x >> 6;
  const int h = hq * 4 + hl;
  const int w = threadIdx.x & 63;
  if (w < WW) {
    const float* src = x + (size_t)b * CH * HWPIX + h * WW + w;
    const int pos = hl * WW + w;
    #pragma unroll 4
    for (int c0 = 0; c0 < CH; c0 += 8) {
      bfv8 v;
      #pragma unroll
      for (int k = 0; k < 8; ++k) v[k] = f2bf(src[(size_t)(c0 + k) * HWPIX]);
      const int idx = (pos * CH + c0) ^ ((pos & 7) << 3);
      *(bfv8*)(tile + idx) = v;
    }
  }
  __syncthreads();
  unsigned short* out = xT + (size_t)(b * HH + hq * 4) * WW * CH;
  #pragma unroll
  for (int j = 0; j < 14; ++j) {
    const int u = j * 256 + threadIdx.x;
    const int idx = (u * 8) ^ (((u >> 4) & 7) << 3);
    *(bfv8*)(out + u * 8) = *(const bfv8*)(tile + idx);
  }
}

// ---------------------------------------------------------------------------
// K2: weights [B,O,I,3,3] fp32 -> [B,tap,O,I] bf16 (dense reads, 16B writes).
__global__ __launch_bounds__(256)
void prep_w(const float* __restrict__ w1, const float* __restrict__ w2,
            unsigned short* __restrict__ o1, unsigned short* __restrict__ o2) {
  __shared__ unsigned short lw[18432];
  const int id = blockIdx.x;
  const int which = id >> 9;
  const int b = (id >> 3) & 63, ck = id & 7;
  const float* src = (which ? w2 : w1) + ((size_t)b * 16384 + ck * 2048) * 9;
  unsigned short* dst = (which ? o2 : o1);
  const int t = threadIdx.x;
  #pragma unroll
  for (int j = 0; j < 72; ++j)
    lw[j * 256 + t] = f2bf(src[j * 256 + t]);
  __syncthreads();
  const int ol = t >> 4, oct = t & 15;
  #pragma unroll
  for (int tap = 0; tap < 9; ++tap) {
    bfv8 v;
    #pragma unroll
    for (int k = 0; k < 8; ++k) v[k] = lw[(ol * 128 + oct * 8 + k) * 9 + tap];
    *(bfv8*)(dst + ((size_t)(b * 9 + tap) * CH + ck * 16 + ol) * CH + oct * 8) = v;
  }
}

// ---------------------------------------------------------------------------
// K3/K5: per-sample conv, implicit GEMM — R22 structure VERBATIM (101us,
// MfmaUtil 23.4, verified). 28x8 tile + K-split patch: gll count 1008/CU
// (R21's) AND 2 blocks/CU co-residency (R20's) simultaneously.
template<bool FUSE>
__global__ __launch_bounds__(256, 2)
void conv_kernel(const unsigned short* __restrict__ in,
                 const unsigned short* __restrict__ wt,
                 unsigned short* __restrict__ outp,
                 float* __restrict__ partials,
                 const float* __restrict__ tab) {   // [256]: scale | shift (FUSE)
  __shared__ __align__(16) unsigned short patch[20400];  // 300 pos x 68 (64ch)
  __shared__ __align__(16) unsigned short wbuf[12288];   // 4 wv x 3 buf x 1024
  __shared__ float sacc[256];                            // sum[128] | sumsq[128]
  const int xcd = blockIdx.x & 7;
  const int q = blockIdx.x >> 3;                    // 0..111
  const int s = q / 14;
  const int tile = q - s * 14;                      // 0..13
  const int b = s * 8 + xcd;
  const int ty = tile / 7, tx = tile % 7;
  const int h0 = ty * 28, w0 = tx * 8;
  const int t = threadIdx.x;

  const int lane = t & 63, wv = t >> 6;
  const int lrow = lane & 15, lgrp = lane >> 4;
  const int px = lrow & 7, pyl = lrow >> 3;

  sacc[t] = 0.0f;

  // Per-lane global source = lane's A-frag: W[o=wv*32+lrow][lgrp*8..+8].
  const unsigned short* wsrc =
      wt + (size_t)b * 9 * CH * CH + (wv * 32 + lrow) * CH + lgrp * 8;

  // Stage S (0..35): phase = S/18, tap = (S%18)>>1, ic = phase*64+(S&1)*32.
  // 32 O x 32 I = 2KB/wave into wave-private buffer P (2 gll instrs).
#define STAGE(S, P) { \
    const unsigned short* g_ = wsrc + (((S) % 18) >> 1) * (CH * CH) + \
                               ((S) / 18) * 64 + ((S) & 1) * 32; \
    unsigned short* l_ = wbuf + (wv * 3 + (P)) * 1024; \
    __builtin_amdgcn_global_load_lds( \
        (const __attribute__((address_space(1))) void*)g_, \
        (__attribute__((address_space(3))) void*)l_, 16, 0, 0); \
    __builtin_amdgcn_global_load_lds( \
        (const __attribute__((address_space(1))) void*)(g_ + 16 * CH), \
        (__attribute__((address_space(3))) void*)(l_ + 512), 16, 0, 0); \
  }

  // Patch staging for channel-half PH: 300 positions x 64 ch (128B each).
#define STAGE_PATCH(PH) { \
    for (int u = t; u < 300; u += 256) { \
      const int dh = u / 10, dw = u - dh * 10; \
      const int h = h0 + dh - 1, w = w0 + dw - 1; \
      unsigned short* ld = &patch[u * 68]; \
      if (h >= 0 && h < HH && w >= 0 && w < WW) { \
        const unsigned short* src = \
            in + ((size_t)((b * HH + h) * WW + w)) * CH + (PH) * 64; \
        if (FUSE) { \
          for (int j = 0; j < 8; ++j) { \
            const bfv8 v = *(const bfv8*)(src + j * 8); \
            bfv8 o; \
            for (int k = 0; k < 8; ++k) { \
              const int c = (PH) * 64 + j * 8 + k; \
              o[k] = f2bf(fmaxf(bf2f(v[k]) * tab[c] + tab[CH + c], 0.0f)); \
            } \
            *(bfv8*)(ld + j * 8) = o; \
          } \
        } else { \
          for (int j = 0; j < 8; ++j) \
            *(bfv8*)(ld + j * 8) = *(const bfv8*)(src + j * 8); \
        } \
      } else { \
        const bfv8 z = {0, 0, 0, 0, 0, 0, 0, 0}; \
        for (int j = 0; j < 8; ++j) *(bfv8*)(ld + j * 8) = z; \
      } \
    } }

  // COMPUTE(S,P): 2 A-frags lane-linear from wave-private buf P,
  // 14 B-frags from patch (ic chunk = S&1 within the 64-wide rows), 28 MFMA.
#define COMPUTE(S, P) { \
    const int tap_ = ((S) % 18) >> 1, icl_ = (S) & 1; \
    const int pb_ = (pyl + tap_ / 3) * 10 + px + tap_ % 3; \
    const unsigned short* ab_ = wbuf + (wv * 3 + (P)) * 1024 + lane * 8; \
    const short8v a0_ = *(const short8v*)(ab_); \
    const short8v a1_ = *(const short8v*)(ab_ + 512); \
    _Pragma("unroll") \
    for (int nf = 0; nf < 14; ++nf) { \
      const short8v bfr = *(const short8v*)( \
          &patch[(pb_ + nf * 20) * 68 + icl_ * 32 + lgrp * 8]); \
      acc[0][nf] = __builtin_amdgcn_mfma_f32_16x16x32_bf16(a0_, bfr, acc[0][nf], 0, 0, 0); \
      acc[1][nf] = __builtin_amdgcn_mfma_f32_16x16x32_bf16(a1_, bfr, acc[1][nf], 0, 0, 0); \
    } }

#define RUN(S) \
    __builtin_amdgcn_sched_barrier(0); \
    STAGE((S) + 2, ((S) + 2) % 3) \
    asm volatile("s_waitcnt vmcnt(4)" ::: "memory"); \
    __builtin_amdgcn_sched_barrier(0); \
    COMPUTE(S, (S) % 3)

  // ---- Phase 0: I in [0,64) ----
  STAGE(0, 0)
  STAGE_PATCH(0)
  __syncthreads();

  f32x4 acc[2][14];
  #pragma unroll
  for (int m = 0; m < 2; ++m)
    #pragma unroll
    for (int n = 0; n < 14; ++n) acc[m][n] = (f32x4){0.f, 0.f, 0.f, 0.f};

  STAGE(1, 1)
  RUN(0)  RUN(1)  RUN(2)  RUN(3)  RUN(4)  RUN(5)  RUN(6)  RUN(7)
  RUN(8)  RUN(9)  RUN(10) RUN(11) RUN(12) RUN(13) RUN(14) RUN(15)
  __builtin_amdgcn_sched_barrier(0);
  asm volatile("s_waitcnt vmcnt(2)" ::: "memory");
  __builtin_amdgcn_sched_barrier(0);
  COMPUTE(16, 1)
  __builtin_amdgcn_sched_barrier(0);
  asm volatile("s_waitcnt vmcnt(0)" ::: "memory");
  __builtin_amdgcn_sched_barrier(0);
  COMPUTE(17, 2)

  // ---- Phase boundary: restage patch with I in [64,128) ----
  STAGE(18, 0)            // drained resident by the barrier below
  __syncthreads();        // all phase-0 patch reads done
  STAGE_PATCH(1)
  __syncthreads();        // new patch ready

  STAGE(19, 1)
  RUN(18) RUN(19) RUN(20) RUN(21) RUN(22) RUN(23) RUN(24) RUN(25)
  RUN(26) RUN(27) RUN(28) RUN(29) RUN(30) RUN(31) RUN(32) RUN(33)
  __builtin_amdgcn_sched_barrier(0);
  asm volatile("s_waitcnt vmcnt(2)" ::: "memory");
  __builtin_amdgcn_sched_barrier(0);
  COMPUTE(34, 1)
  __builtin_amdgcn_sched_barrier(0);
  asm volatile("s_waitcnt vmcnt(0)" ::: "memory");
  __builtin_amdgcn_sched_barrier(0);
  COMPUTE(35, 2)
#undef RUN
#undef COMPUTE
#undef STAGE
#undef STAGE_PATCH

  __syncthreads();   // all patch reads done; reuse patch as output buffer

  // Fused BN stat partials (uses acc only; sacc atomics complete before the
  // next barrier).
  #pragma unroll
  for (int mf = 0; mf < 2; ++mf) {
    f32x4 sv4 = {0.f, 0.f, 0.f, 0.f}, qv4 = {0.f, 0.f, 0.f, 0.f};
    #pragma unroll
    for (int nf = 0; nf < 14; ++nf) {
      const f32x4 v = acc[mf][nf];
      sv4 += v;
      qv4 += v * v;
    }
    #pragma unroll
    for (int r = 0; r < 4; ++r) {
      float sv = sv4[r], qv = qv4[r];
      sv += __shfl_xor(sv, 1, 64);  qv += __shfl_xor(qv, 1, 64);
      sv += __shfl_xor(sv, 2, 64);  qv += __shfl_xor(qv, 2, 64);
      sv += __shfl_xor(sv, 4, 64);  qv += __shfl_xor(qv, 4, 64);
      sv += __shfl_xor(sv, 8, 64);  qv += __shfl_xor(qv, 8, 64);
      if (lrow == 0) {
        const int ch = wv * 32 + mf * 16 + lgrp * 4 + r;
        atomicAdd(&sacc[ch], sv);
        atomicAdd(&sacc[CH + ch], qv);
      }
    }
  }

  // Epilogue: two 112-px passes through obuf (28,672B <= patch region).
  char* obuf = (char*)patch;
  #pragma unroll
  for (int a = 0; a < 2; ++a) {
    if (a) __syncthreads();            // previous copy-out reads done
    #pragma unroll
    for (int mf = 0; mf < 2; ++mf) {
      #pragma unroll
      for (int m = 0; m < 7; ++m) {
        const f32x4 v = acc[mf][a * 7 + m];
        bfv4 pk;
        #pragma unroll
        for (int r = 0; r < 4; ++r) pk[r] = f2bf(v[r]);
        const int p = (m * 2 + pyl) * 8 + px;          // 0..111 within pass
        const int ch = wv * 32 + mf * 16 + lgrp * 4;
        int byte = p * 256 + ch * 2;
        byte ^= ((byte >> 8) & 3) << 5;
        *(bfv4*)(obuf + byte) = pk;
      }
    }
    __syncthreads();
    if (a == 0) partials[(size_t)blockIdx.x * 256 + t] = sacc[t];
    // Copy out 112 px x 128 ch = 1792 x 16B units.
    #pragma unroll
    for (int j = 0; j < 7; ++j) {
      const int u = j * 256 + t;
      int byte = u * 16;
      byte ^= ((byte >> 8) & 3) << 5;
      const bfv8 v = *(const bfv8*)(obuf + byte);
      const int pix = u >> 4, py = pix >> 3, pxx = pix & 7;
      *(bfv8*)(outp + ((size_t)((b * HH + h0 + a * 14 + py) * WW + (w0 + pxx))) * CH +
               (u & 15) * 8) = v;
    }
  }
}

// ---------------------------------------------------------------------------
// K-red: reduce partials[896][256] -> st[256]. 32 blocks x 256 thr.
__global__ __launch_bounds__(256)
void stat_reduce(const float* __restrict__ partials, float* __restrict__ st) {
  const int t = threadIdx.x;
  float s = 0.0f;
  const int i0 = blockIdx.x * (NCONVBLK / 32);
  for (int i = 0; i < NCONVBLK / 32; ++i)
    s += partials[(size_t)(i0 + i) * 256 + t];
  atomicAdd(&st[t], s);
}

// ---------------------------------------------------------------------------
// K4/K6: per-channel BN stats -> scale/shift tables.
__global__ __launch_bounds__(128)
void bn_stats(const float* __restrict__ st, const float* __restrict__ gamma,
              const float* __restrict__ beta, float* __restrict__ tab) {
  const int c = threadIdx.x;
  const float inv = 1.0f / NPIXF;
  const float mean = st[c] * inv;
  const float var = st[CH + c] * inv - mean * mean;
  const float s = gamma[c] / sqrtf(var + 1e-5f);
  tab[c] = s;
  tab[CH + c] = beta[c] - mean * s;
}

// ---------------------------------------------------------------------------
// K7 (R23): out = relu(scale2*y2 + shift2 + residual), NHWC bf16 -> NCHW
// fp32 via LDS TRANSPOSE. The old kernel read ys[c]/rs[c] with 256B lane
// stride -- every bf16 read was a 64-line scatter (101us vs 49us HBM floor).
// New: phase 1 reads each pixel's channels COALESCED (bfv8), computes fp32,
// scatters into transposed tile[c][113] (lanes consecutive pix ->
// conflict-free; 113-word row stride). Phase 2 writes NCHW with lanes
// consecutive in w (224B coalesced per c), reading tile[c][pos] at
// consecutive banks. 2 h-rows/block, LDS 57.9KB -> 2 blocks/CU.
template<bool BF16RES>
__global__ __launch_bounds__(256)
void final_kernel(const unsigned short* __restrict__ y2,
                  const unsigned short* __restrict__ xbf,
                  const float* __restrict__ x,
                  const float* __restrict__ tab, float* __restrict__ out) {
  __shared__ float tile[CH * 113];                  // [c][pos], pos 0..111
  const int bid = blockIdx.x;
  const int b = bid / 28, hp = bid % 28;
  const int h0 = hp * 2;
  const int t = threadIdx.x;

  if (t < 224) {                                    // pix 0..111, half 0..1
    const int pix = t >> 1, half = t & 1;
    const int h = h0 + pix / 56, w = pix % 56;
    const size_t base = ((size_t)((b * HH + h) * WW + w)) * CH + half * 64;
    const unsigned short* ys = y2 + base;
    const unsigned short* rs = xbf + base;
    const float* xs = x + (size_t)b * CH * HWPIX + h * WW + w;
    #pragma unroll
    for (int j = 0; j < 8; ++j) {
      const bfv8 v = *(const bfv8*)(ys + j * 8);
      bfv8 r;
      if (BF16RES) r = *(const bfv8*)(rs + j * 8);
      #pragma unroll
      for (int k = 0; k < 8; ++k) {
        const int c = half * 64 + j * 8 + k;
        const float res = BF16RES ? bf2f(r[k]) : xs[(size_t)c * HWPIX];
        tile[c * 113 + pix] =
            fmaxf(bf2f(v[k]) * tab[c] + tab[CH + c] + res, 0.0f);
      }
    }
  }
  __syncthreads();

  const int w = t & 63, hl = (t >> 6) & 1, cg = t >> 7;  // cg 0..1
  if (w < WW) {
    const int pos = hl * 56 + w;
    float* os = out + (size_t)b * CH * HWPIX + (size_t)(h0 + hl) * WW + w;
    #pragma unroll
    for (int c0 = 0; c0 < 64; ++c0) {
      const int c = cg * 64 + c0;
      os[(size_t)c * HWPIX] = tile[c * 113 + pos];
    }
  }
}

// ---------------------------------------------------------------------------
extern "C" void kernel_launch(void* const* d_in, const int* in_sizes, int n_in,
                              void* d_out, int out_size, void* d_ws, size_t ws_size,
                              hipStream_t stream) {
  const float* x  = (const float*)d_in[0];
  const float* w1 = (const float*)d_in[1];
  const float* w2 = (const float*)d_in[2];
  const float* g1 = (const float*)d_in[3];
  const float* b1 = (const float*)d_in[4];
  const float* g2 = (const float*)d_in[5];
  const float* b2 = (const float*)d_in[6];
  float* out = (float*)d_out;

  // Workspace layout (bytes):
  //   xT   0            51,380,224
  //   y1   51,380,224   51,380,224
  //   w1b  102,760,448  18,874,368
  //   w2b  121,634,816  18,874,368
  //   p1   140,509,184  3,211,264   (896 x 256 floats used)
  //   p2   143,720,448  3,211,264
  //   st   146,931,712  4,096   (st1|st2|tab1|tab2, 256 floats each)
  //   y2   146,935,808  51,380,224  (optional, if ws_size allows)
  char* ws = (char*)d_ws;
  unsigned short* xT  = (unsigned short*)(ws);
  unsigned short* y1  = (unsigned short*)(ws + 51380224);
  unsigned short* w1b = (unsigned short*)(ws + 102760448);
  unsigned short* w2b = (unsigned short*)(ws + 121634816);
  float*          p1  = (float*)(ws + 140509184);
  float*          p2  = (float*)(ws + 143720448);
  float*          st  = (float*)(ws + 146931712);
  const bool sepY2 = ws_size >= (size_t)146935808 + 51380224;
  unsigned short* y2  = sepY2 ? (unsigned short*)(ws + 146935808) : xT;

  (void)hipMemsetAsync(st, 0, 2048, stream);  // zero st1+st2

  hipLaunchKernelGGL(prep_x, dim3(NB * 14), dim3(256), 0, stream, x, xT);
  hipLaunchKernelGGL(prep_w, dim3(1024), dim3(256), 0, stream, w1, w2, w1b, w2b);
  hipLaunchKernelGGL((conv_kernel<false>), dim3(NCONVBLK), dim3(256), 0, stream,
                     xT, w1b, y1, p1, (const float*)nullptr);
  hipLaunchKernelGGL(stat_reduce, dim3(32), dim3(256), 0, stream, p1, st);
  hipLaunchKernelGGL(bn_stats, dim3(1), dim3(128), 0, stream, st, g1, b1, st + 512);
  hipLaunchKernelGGL((conv_kernel<true>), dim3(NCONVBLK), dim3(256), 0, stream,
                     y1, w2b, y2, p2, st + 512);
  hipLaunchKernelGGL(stat_reduce, dim3(32), dim3(256), 0, stream, p2, st + 256);
  hipLaunchKernelGGL(bn_stats, dim3(1), dim3(128), 0, stream, st + 256, g2, b2, st + 768);
  if (sepY2) {
    hipLaunchKernelGGL((final_kernel<true>), dim3(NB * 28), dim3(256), 0, stream,
                       y2, xT, x, st + 768, out);
  } else {
    hipLaunchKernelGGL((final_kernel<false>), dim3(NB * 28), dim3(256), 0, stream,
                       y2, xT, x, st + 768, out);
  }
}

// Round 16
// 274.668 us; speedup vs baseline: 1.3856x; 1.0925x over previous
//
#include <hip/hip_runtime.h>
#include <hip/hip_bf16.h>
#include <stdint.h>
#include <stddef.h>

// Problem dims (fixed): B=64, C=128, H=W=56, 3x3 conv pad=1 stride=1.
#define CH 128
#define HH 56
#define WW 56
#define HWPIX (HH*WW)        // 3136
#define NB 64
#define NPIXF 200704.0f      // B*H*W
#define NCONVBLK 896         // 64 samples x 14 tiles (28x8 px)
#define PSTR 72              // patch row stride in shorts (144B = 4-bank class)

typedef __attribute__((ext_vector_type(8))) short short8v;    // 8 bf16 -> MFMA A/B frag
typedef __attribute__((ext_vector_type(8))) unsigned short bfv8;
typedef __attribute__((ext_vector_type(4))) unsigned short bfv4;
typedef __attribute__((ext_vector_type(4))) float f32x4;

__device__ __forceinline__ unsigned short f2bf(float f) {
  unsigned int u = __float_as_uint(f);
  u += 0x7fffu + ((u >> 16) & 1u);            // RNE
  return (unsigned short)(u >> 16);
}
__device__ __forceinline__ float bf2f(unsigned short s) {
  return __uint_as_float(((unsigned int)s) << 16);
}

// ---------------------------------------------------------------------------
// K1: x NCHW fp32 -> NHWC bf16 (LDS transpose, coalesced 16B/lane writes).
__global__ __launch_bounds__(256)
void prep_x(const float* __restrict__ x, unsigned short* __restrict__ xT) {
  __shared__ unsigned short tile[4 * 56 * 128];
  const int bid = blockIdx.x;
  const int b = bid / 14, hq = bid % 14;
  const int hl = threadIdx.x >> 6;
  const int h = hq * 4 + hl;
  const int w = threadIdx.x & 63;
  if (w < WW) {
    const float* src = x + (size_t)b * CH * HWPIX + h * WW + w;
    const int pos = hl * WW + w;
    #pragma unroll 4
    for (int c0 = 0; c0 < CH; c0 += 8) {
      bfv8 v;
      #pragma unroll
      for (int k = 0; k < 8; ++k) v[k] = f2bf(src[(size_t)(c0 + k) * HWPIX]);
      const int idx = (pos * CH + c0) ^ ((pos & 7) << 3);
      *(bfv8*)(tile + idx) = v;
    }
  }
  __syncthreads();
  unsigned short* out = xT + (size_t)(b * HH + hq * 4) * WW * CH;
  #pragma unroll
  for (int j = 0; j < 14; ++j) {
    const int u = j * 256 + threadIdx.x;
    const int idx = (u * 8) ^ (((u >> 4) & 7) << 3);
    *(bfv8*)(out + u * 8) = *(const bfv8*)(tile + idx);
  }
}

// ---------------------------------------------------------------------------
// K2: weights [B,O,I,3,3] fp32 -> [B,tap,O,I] bf16 (dense reads, 16B writes).
__global__ __launch_bounds__(256)
void prep_w(const float* __restrict__ w1, const float* __restrict__ w2,
            unsigned short* __restrict__ o1, unsigned short* __restrict__ o2) {
  __shared__ unsigned short lw[18432];
  const int id = blockIdx.x;
  const int which = id >> 9;
  const int b = (id >> 3) & 63, ck = id & 7;
  const float* src = (which ? w2 : w1) + ((size_t)b * 16384 + ck * 2048) * 9;
  unsigned short* dst = (which ? o2 : o1);
  const int t = threadIdx.x;
  #pragma unroll
  for (int j = 0; j < 72; ++j)
    lw[j * 256 + t] = f2bf(src[j * 256 + t]);
  __syncthreads();
  const int ol = t >> 4, oct = t & 15;
  #pragma unroll
  for (int tap = 0; tap < 9; ++tap) {
    bfv8 v;
    #pragma unroll
    for (int k = 0; k < 8; ++k) v[k] = lw[(ol * 128 + oct * 8 + k) * 9 + tap];
    *(bfv8*)(dst + ((size_t)(b * 9 + tap) * CH + ck * 16 + ol) * CH + oct * 8) = v;
  }
}

// ---------------------------------------------------------------------------
// K3/K5: per-sample conv, implicit GEMM — R22 structure; R24 changes ONLY
// the K-split patch row stride 68 -> 72 shorts. R22's 68-stride (136B = 2
// banks mod 32) made B-frag ds_read_b128 start-banks uneven (conflicts
// 9.0M -> 15.65M, ~10us/dispatch). 72 shorts = 144B = 4-bank class: starts
// 4(i+lgrp) give exactly 8 accesses/bank = wave64-b128 minimum ->
// conflict-free reads AND writes. LDS 43.2K patch + 12.3K wbuf + 1K sacc
// = 56.5KB -> still 2 blocks/CU.
// Predict: conflicts <=9M, conv 101->92-97, total ~283-292. Null (+-2us):
// conflicts off critical path -> conv near structural floor.
template<bool FUSE>
__global__ __launch_bounds__(256, 2)
void conv_kernel(const unsigned short* __restrict__ in,
                 const unsigned short* __restrict__ wt,
                 unsigned short* __restrict__ outp,
                 float* __restrict__ partials,
                 const float* __restrict__ tab) {   // [256]: scale | shift (FUSE)
  __shared__ __align__(16) unsigned short patch[300 * PSTR]; // 300 pos x 64ch
  __shared__ __align__(16) unsigned short wbuf[12288];   // 4 wv x 3 buf x 1024
  __shared__ float sacc[256];                            // sum[128] | sumsq[128]
  const int xcd = blockIdx.x & 7;
  const int q = blockIdx.x >> 3;                    // 0..111
  const int s = q / 14;
  const int tile = q - s * 14;                      // 0..13
  const int b = s * 8 + xcd;
  const int ty = tile / 7, tx = tile % 7;
  const int h0 = ty * 28, w0 = tx * 8;
  const int t = threadIdx.x;

  const int lane = t & 63, wv = t >> 6;
  const int lrow = lane & 15, lgrp = lane >> 4;
  const int px = lrow & 7, pyl = lrow >> 3;

  sacc[t] = 0.0f;

  // Per-lane global source = lane's A-frag: W[o=wv*32+lrow][lgrp*8..+8].
  const unsigned short* wsrc =
      wt + (size_t)b * 9 * CH * CH + (wv * 32 + lrow) * CH + lgrp * 8;

  // Stage S (0..35): phase = S/18, tap = (S%18)>>1, ic = phase*64+(S&1)*32.
  // 32 O x 32 I = 2KB/wave into wave-private buffer P (2 gll instrs).
#define STAGE(S, P) { \
    const unsigned short* g_ = wsrc + (((S) % 18) >> 1) * (CH * CH) + \
                               ((S) / 18) * 64 + ((S) & 1) * 32; \
    unsigned short* l_ = wbuf + (wv * 3 + (P)) * 1024; \
    __builtin_amdgcn_global_load_lds( \
        (const __attribute__((address_space(1))) void*)g_, \
        (__attribute__((address_space(3))) void*)l_, 16, 0, 0); \
    __builtin_amdgcn_global_load_lds( \
        (const __attribute__((address_space(1))) void*)(g_ + 16 * CH), \
        (__attribute__((address_space(3))) void*)(l_ + 512), 16, 0, 0); \
  }

  // Patch staging for channel-half PH: 300 positions x 64 ch (128B each).
#define STAGE_PATCH(PH) { \
    for (int u = t; u < 300; u += 256) { \
      const int dh = u / 10, dw = u - dh * 10; \
      const int h = h0 + dh - 1, w = w0 + dw - 1; \
      unsigned short* ld = &patch[u * PSTR]; \
      if (h >= 0 && h < HH && w >= 0 && w < WW) { \
        const unsigned short* src = \
            in + ((size_t)((b * HH + h) * WW + w)) * CH + (PH) * 64; \
        if (FUSE) { \
          for (int j = 0; j < 8; ++j) { \
            const bfv8 v = *(const bfv8*)(src + j * 8); \
            bfv8 o; \
            for (int k = 0; k < 8; ++k) { \
              const int c = (PH) * 64 + j * 8 + k; \
              o[k] = f2bf(fmaxf(bf2f(v[k]) * tab[c] + tab[CH + c], 0.0f)); \
            } \
            *(bfv8*)(ld + j * 8) = o; \
          } \
        } else { \
          for (int j = 0; j < 8; ++j) \
            *(bfv8*)(ld + j * 8) = *(const bfv8*)(src + j * 8); \
        } \
      } else { \
        const bfv8 z = {0, 0, 0, 0, 0, 0, 0, 0}; \
        for (int j = 0; j < 8; ++j) *(bfv8*)(ld + j * 8) = z; \
      } \
    } }

  // COMPUTE(S,P): 2 A-frags lane-linear from wave-private buf P,
  // 14 B-frags from patch (ic chunk = S&1 within the 64-wide rows), 28 MFMA.
#define COMPUTE(S, P) { \
    const int tap_ = ((S) % 18) >> 1, icl_ = (S) & 1; \
    const int pb_ = (pyl + tap_ / 3) * 10 + px + tap_ % 3; \
    const unsigned short* ab_ = wbuf + (wv * 3 + (P)) * 1024 + lane * 8; \
    const short8v a0_ = *(const short8v*)(ab_); \
    const short8v a1_ = *(const short8v*)(ab_ + 512); \
    _Pragma("unroll") \
    for (int nf = 0; nf < 14; ++nf) { \
      const short8v bfr = *(const short8v*)( \
          &patch[(pb_ + nf * 20) * PSTR + icl_ * 32 + lgrp * 8]); \
      acc[0][nf] = __builtin_amdgcn_mfma_f32_16x16x32_bf16(a0_, bfr, acc[0][nf], 0, 0, 0); \
      acc[1][nf] = __builtin_amdgcn_mfma_f32_16x16x32_bf16(a1_, bfr, acc[1][nf], 0, 0, 0); \
    } }

#define RUN(S) \
    __builtin_amdgcn_sched_barrier(0); \
    STAGE((S) + 2, ((S) + 2) % 3) \
    asm volatile("s_waitcnt vmcnt(4)" ::: "memory"); \
    __builtin_amdgcn_sched_barrier(0); \
    COMPUTE(S, (S) % 3)

  // ---- Phase 0: I in [0,64) ----
  STAGE(0, 0)
  STAGE_PATCH(0)
  __syncthreads();

  f32x4 acc[2][14];
  #pragma unroll
  for (int m = 0; m < 2; ++m)
    #pragma unroll
    for (int n = 0; n < 14; ++n) acc[m][n] = (f32x4){0.f, 0.f, 0.f, 0.f};

  STAGE(1, 1)
  RUN(0)  RUN(1)  RUN(2)  RUN(3)  RUN(4)  RUN(5)  RUN(6)  RUN(7)
  RUN(8)  RUN(9)  RUN(10) RUN(11) RUN(12) RUN(13) RUN(14) RUN(15)
  __builtin_amdgcn_sched_barrier(0);
  asm volatile("s_waitcnt vmcnt(2)" ::: "memory");
  __builtin_amdgcn_sched_barrier(0);
  COMPUTE(16, 1)
  __builtin_amdgcn_sched_barrier(0);
  asm volatile("s_waitcnt vmcnt(0)" ::: "memory");
  __builtin_amdgcn_sched_barrier(0);
  COMPUTE(17, 2)

  // ---- Phase boundary: restage patch with I in [64,128) ----
  STAGE(18, 0)            // drained resident by the barrier below
  __syncthreads();        // all phase-0 patch reads done
  STAGE_PATCH(1)
  __syncthreads();        // new patch ready

  STAGE(19, 1)
  RUN(18) RUN(19) RUN(20) RUN(21) RUN(22) RUN(23) RUN(24) RUN(25)
  RUN(26) RUN(27) RUN(28) RUN(29) RUN(30) RUN(31) RUN(32) RUN(33)
  __builtin_amdgcn_sched_barrier(0);
  asm volatile("s_waitcnt vmcnt(2)" ::: "memory");
  __builtin_amdgcn_sched_barrier(0);
  COMPUTE(34, 1)
  __builtin_amdgcn_sched_barrier(0);
  asm volatile("s_waitcnt vmcnt(0)" ::: "memory");
  __builtin_amdgcn_sched_barrier(0);
  COMPUTE(35, 2)
#undef RUN
#undef COMPUTE
#undef STAGE
#undef STAGE_PATCH

  __syncthreads();   // all patch reads done; reuse patch as output buffer

  // Fused BN stat partials (uses acc only; sacc atomics complete before the
  // next barrier).
  #pragma unroll
  for (int mf = 0; mf < 2; ++mf) {
    f32x4 sv4 = {0.f, 0.f, 0.f, 0.f}, qv4 = {0.f, 0.f, 0.f, 0.f};
    #pragma unroll
    for (int nf = 0; nf < 14; ++nf) {
      const f32x4 v = acc[mf][nf];
      sv4 += v;
      qv4 += v * v;
    }
    #pragma unroll
    for (int r = 0; r < 4; ++r) {
      float sv = sv4[r], qv = qv4[r];
      sv += __shfl_xor(sv, 1, 64);  qv += __shfl_xor(qv, 1, 64);
      sv += __shfl_xor(sv, 2, 64);  qv += __shfl_xor(qv, 2, 64);
      sv += __shfl_xor(sv, 4, 64);  qv += __shfl_xor(qv, 4, 64);
      sv += __shfl_xor(sv, 8, 64);  qv += __shfl_xor(qv, 8, 64);
      if (lrow == 0) {
        const int ch = wv * 32 + mf * 16 + lgrp * 4 + r;
        atomicAdd(&sacc[ch], sv);
        atomicAdd(&sacc[CH + ch], qv);
      }
    }
  }

  // Epilogue: two 112-px passes through obuf (28,672B <= patch region).
  char* obuf = (char*)patch;
  #pragma unroll
  for (int a = 0; a < 2; ++a) {
    if (a) __syncthreads();            // previous copy-out reads done
    #pragma unroll
    for (int mf = 0; mf < 2; ++mf) {
      #pragma unroll
      for (int m = 0; m < 7; ++m) {
        const f32x4 v = acc[mf][a * 7 + m];
        bfv4 pk;
        #pragma unroll
        for (int r = 0; r < 4; ++r) pk[r] = f2bf(v[r]);
        const int p = (m * 2 + pyl) * 8 + px;          // 0..111 within pass
        const int ch = wv * 32 + mf * 16 + lgrp * 4;
        int byte = p * 256 + ch * 2;
        byte ^= ((byte >> 8) & 3) << 5;
        *(bfv4*)(obuf + byte) = pk;
      }
    }
    __syncthreads();
    if (a == 0) partials[(size_t)blockIdx.x * 256 + t] = sacc[t];
    // Copy out 112 px x 128 ch = 1792 x 16B units.
    #pragma unroll
    for (int j = 0; j < 7; ++j) {
      const int u = j * 256 + t;
      int byte = u * 16;
      byte ^= ((byte >> 8) & 3) << 5;
      const bfv8 v = *(const bfv8*)(obuf + byte);
      const int pix = u >> 4, py = pix >> 3, pxx = pix & 7;
      *(bfv8*)(outp + ((size_t)((b * HH + h0 + a * 14 + py) * WW + (w0 + pxx))) * CH +
               (u & 15) * 8) = v;
    }
  }
}

// ---------------------------------------------------------------------------
// K-red: reduce partials[896][256] -> st[256]. 32 blocks x 256 thr.
__global__ __launch_bounds__(256)
void stat_reduce(const float* __restrict__ partials, float* __restrict__ st) {
  const int t = threadIdx.x;
  float s = 0.0f;
  const int i0 = blockIdx.x * (NCONVBLK / 32);
  for (int i = 0; i < NCONVBLK / 32; ++i)
    s += partials[(size_t)(i0 + i) * 256 + t];
  atomicAdd(&st[t], s);
}

// ---------------------------------------------------------------------------
// K4/K6: per-channel BN stats -> scale/shift tables.
__global__ __launch_bounds__(128)
void bn_stats(const float* __restrict__ st, const float* __restrict__ gamma,
              const float* __restrict__ beta, float* __restrict__ tab) {
  const int c = threadIdx.x;
  const float inv = 1.0f / NPIXF;
  const float mean = st[c] * inv;
  const float var = st[CH + c] * inv - mean * mean;
  const float s = gamma[c] / sqrtf(var + 1e-5f);
  tab[c] = s;
  tab[CH + c] = beta[c] - mean * s;
}

// ---------------------------------------------------------------------------
// K7 (R23, verified): out = relu(scale2*y2 + shift2 + residual), NHWC bf16
// -> NCHW fp32 via LDS transpose. Coalesced channel reads (bfv8), transposed
// tile[c][113], coalesced w-contiguous NCHW writes. 2 h-rows/block.
template<bool BF16RES>
__global__ __launch_bounds__(256)
void final_kernel(const unsigned short* __restrict__ y2,
                  const unsigned short* __restrict__ xbf,
                  const float* __restrict__ x,
                  const float* __restrict__ tab, float* __restrict__ out) {
  __shared__ float tile[CH * 113];                  // [c][pos], pos 0..111
  const int bid = blockIdx.x;
  const int b = bid / 28, hp = bid % 28;
  const int h0 = hp * 2;
  const int t = threadIdx.x;

  if (t < 224) {                                    // pix 0..111, half 0..1
    const int pix = t >> 1, half = t & 1;
    const int h = h0 + pix / 56, w = pix % 56;
    const size_t base = ((size_t)((b * HH + h) * WW + w)) * CH + half * 64;
    const unsigned short* ys = y2 + base;
    const unsigned short* rs = xbf + base;
    const float* xs = x + (size_t)b * CH * HWPIX + h * WW + w;
    #pragma unroll
    for (int j = 0; j < 8; ++j) {
      const bfv8 v = *(const bfv8*)(ys + j * 8);
      bfv8 r;
      if (BF16RES) r = *(const bfv8*)(rs + j * 8);
      #pragma unroll
      for (int k = 0; k < 8; ++k) {
        const int c = half * 64 + j * 8 + k;
        const float res = BF16RES ? bf2f(r[k]) : xs[(size_t)c * HWPIX];
        tile[c * 113 + pix] =
            fmaxf(bf2f(v[k]) * tab[c] + tab[CH + c] + res, 0.0f);
      }
    }
  }
  __syncthreads();

  const int w = t & 63, hl = (t >> 6) & 1, cg = t >> 7;  // cg 0..1
  if (w < WW) {
    const int pos = hl * 56 + w;
    float* os = out + (size_t)b * CH * HWPIX + (size_t)(h0 + hl) * WW + w;
    #pragma unroll
    for (int c0 = 0; c0 < 64; ++c0) {
      const int c = cg * 64 + c0;
      os[(size_t)c * HWPIX] = tile[c * 113 + pos];
    }
  }
}

// ---------------------------------------------------------------------------
extern "C" void kernel_launch(void* const* d_in, const int* in_sizes, int n_in,
                              void* d_out, int out_size, void* d_ws, size_t ws_size,
                              hipStream_t stream) {
  const float* x  = (const float*)d_in[0];
  const float* w1 = (const float*)d_in[1];
  const float* w2 = (const float*)d_in[2];
  const float* g1 = (const float*)d_in[3];
  const float* b1 = (const float*)d_in[4];
  const float* g2 = (const float*)d_in[5];
  const float* b2 = (const float*)d_in[6];
  float* out = (float*)d_out;

  // Workspace layout (bytes):
  //   xT   0            51,380,224
  //   y1   51,380,224   51,380,224
  //   w1b  102,760,448  18,874,368
  //   w2b  121,634,816  18,874,368
  //   p1   140,509,184  3,211,264   (896 x 256 floats used)
  //   p2   143,720,448  3,211,264
  //   st   146,931,712  4,096   (st1|st2|tab1|tab2, 256 floats each)
  //   y2   146,935,808  51,380,224  (optional, if ws_size allows)
  char* ws = (char*)d_ws;
  unsigned short* xT  = (unsigned short*)(ws);
  unsigned short* y1  = (unsigned short*)(ws + 51380224);
  unsigned short* w1b = (unsigned short*)(ws + 102760448);
  unsigned short* w2b = (unsigned short*)(ws + 121634816);
  float*          p1  = (float*)(ws + 140509184);
  float*          p2  = (float*)(ws + 143720448);
  float*          st  = (float*)(ws + 146931712);
  const bool sepY2 = ws_size >= (size_t)146935808 + 51380224;
  unsigned short* y2  = sepY2 ? (unsigned short*)(ws + 146935808) : xT;

  (void)hipMemsetAsync(st, 0, 2048, stream);  // zero st1+st2

  hipLaunchKernelGGL(prep_x, dim3(NB * 14), dim3(256), 0, stream, x, xT);
  hipLaunchKernelGGL(prep_w, dim3(1024), dim3(256), 0, stream, w1, w2, w1b, w2b);
  hipLaunchKernelGGL((conv_kernel<false>), dim3(NCONVBLK), dim3(256), 0, stream,
                     xT, w1b, y1, p1, (const float*)nullptr);
  hipLaunchKernelGGL(stat_reduce, dim3(32), dim3(256), 0, stream, p1, st);
  hipLaunchKernelGGL(bn_stats, dim3(1), dim3(128), 0, stream, st, g1, b1, st + 512);
  hipLaunchKernelGGL((conv_kernel<true>), dim3(NCONVBLK), dim3(256), 0, stream,
                     y1, w2b, y2, p2, st + 512);
  hipLaunchKernelGGL(stat_reduce, dim3(32), dim3(256), 0, stream, p2, st + 256);
  hipLaunchKernelGGL(bn_stats, dim3(1), dim3(128), 0, stream, st + 256, g2, b2, st + 768);
  if (sepY2) {
    hipLaunchKernelGGL((final_kernel<true>), dim3(NB * 28), dim3(256), 0, stream,
                       y2, xT, x, st + 768, out);
  } else {
    hipLaunchKernelGGL((final_kernel<false>), dim3(NB * 28), dim3(256), 0, stream,
                       y2, xT, x, st + 768, out);
  }
}